// Round 2
// 362.423 us; speedup vs baseline: 1.1065x; 1.1065x over previous
//
#include <hip/hip_runtime.h>
#include <hip/hip_bf16.h>

typedef unsigned short u16;
typedef __bf16 bf16x8 __attribute__((ext_vector_type(8)));
typedef float f32x4 __attribute__((ext_vector_type(4)));

#define MDIM 16384   // 8 * 2048 rows of x
#define NDIM 2048    // output features
#define KDIM 2048    // input features
#define RANK 16
#define BM 256
#define BN 256
#define BK 64
#define NTILE (KDIM / BK)   // 32 K-tiles
#define NITER (NTILE / 2)   // 16 iterations, 2 K-tiles each

#define WPREP_BLOCKS (NDIM * (KDIM / 4) / 256)          // 4096
#define XCONV_BLOCKS (MDIM * (KDIM / 4) / 256)          // 32768

// ---- fp32 -> bf16 round-to-nearest-even ----
__device__ __forceinline__ u16 f2bf(float f) {
    union { float f; unsigned u; } v; v.f = f;
    unsigned u = v.u;
    u += 0x7FFFu + ((u >> 16) & 1u);   // RNE
    return (u16)(u >> 16);
}

// ---- async global->LDS, 16B/lane, dest = wave-uniform base + lane*16 ----
__device__ __forceinline__ void async_copy16(const void* gsrc, void* ldst) {
    __builtin_amdgcn_global_load_lds(
        (const __attribute__((address_space(1))) void*)gsrc,
        (__attribute__((address_space(3))) void*)ldst,
        16, 0, 0);
}

// ============================================================
// Kernel 1 (fused, unchanged): first WPREP_BLOCKS blocks build
// w = W + 2*B@A -> bf16, remaining blocks convert x fp32 -> bf16.
// ============================================================
__global__ __launch_bounds__(256) void prep(const float* __restrict__ x,
                                            const float* __restrict__ W,
                                            const float* __restrict__ Bm,
                                            const float* __restrict__ Am,
                                            u16* __restrict__ xb,
                                            u16* __restrict__ wb) {
    const int bid = blockIdx.x;
    if (bid < WPREP_BLOCKS) {
        int t  = bid * 256 + threadIdx.x;   // 0 .. NDIM*(KDIM/4)-1
        int o  = t >> 9;                    // / (KDIM/4)
        int dq = t & 511;                   // float4 index within row
        float4 acc = ((const float4*)W)[(size_t)o * (KDIM / 4) + dq];
        const float* Bo = Bm + (size_t)o * RANK;
#pragma unroll
        for (int r = 0; r < RANK; ++r) {
            float bv = 2.0f * Bo[r];        // ALPHA/RANK = 2
            float4 a4 = ((const float4*)(Am + (size_t)r * KDIM))[dq];
            acc.x += bv * a4.x; acc.y += bv * a4.y;
            acc.z += bv * a4.z; acc.w += bv * a4.w;
        }
        ushort4 ov;
        ov.x = f2bf(acc.x); ov.y = f2bf(acc.y);
        ov.z = f2bf(acc.z); ov.w = f2bf(acc.w);
        ((ushort4*)wb)[t] = ov;
    } else {
        int t = (bid - WPREP_BLOCKS) * 256 + threadIdx.x;
        float4 v = ((const float4*)x)[t];
        ushort4 o;
        o.x = f2bf(v.x); o.y = f2bf(v.y); o.z = f2bf(v.z); o.w = f2bf(v.w);
        ((ushort4*)xb)[t] = o;
    }
}

// ============================================================
// Kernel 2: 256x256 tile, BK=64, 8 waves (2x4), 8-phase schedule
// with counted vmcnt(4) (T2+T3+T4+T5). Double-buffered 128KB LDS.
//
// Steady-state iteration I computes tiles t=2I (buf0), t+1 (buf1):
//   P1: read buf0 {B all (8), A quad0 (4)}; stage A(t+1)->buf1 (4 loads)
//   P2: read A quad1;                       stage B(t+2) rows 0-127 ->buf0
//   P3: read A quad2;                       stage B(t+2) rows 128-255->buf0
//   P4: read A quad3;                                    vmcnt(4) at end
//   P5: read buf1 {B all, A quad0};         stage A(t+2)->buf0
//   P6: read A quad1;                       stage B(t+3) rows 0-127 ->buf1
//   P7: read A quad2;                       stage B(t+3) rows 128-255->buf1
//   P8: read A quad3;                                    vmcnt(4) at end
// Per-wave vmcnt ledger: 4 ->P1 8 ->P2 10 ->P3 12 ->P4 VM4 retires the 8
// oldest (= exactly the tiles read in P5), symmetric P5-P8. Every LDS
// region is overwritten >=1 barrier after its last read. Swizzle: chunk c
// of row r at slot c^(r&7), via pre-permuted per-lane global source
// (measured 0 bank conflicts in the 128^2 predecessor).
// ============================================================
__global__ __launch_bounds__(512, 2) void gemm_bt(const u16* __restrict__ xb,
                                                  const u16* __restrict__ wb,
                                                  const float* __restrict__ bias,
                                                  float* __restrict__ out) {
    __shared__ __align__(16) u16 lds[2][2][BM * BK];   // [buf][A|B][256*64] = 128 KiB

    const int tid  = threadIdx.x;
    const int lane = tid & 63;
    const int w    = tid >> 6;          // wave 0..7
    const int wm   = w >> 2;            // 0..1 (row half of C tile)
    const int wn   = w & 3;             // 0..3 (col quarter)

    // XCD-aware bijective swizzle: 512 blocks, 512 % 8 == 0
    const int bid = blockIdx.x;
    const int wg  = (bid & 7) * (512 / 8) + (bid >> 3);
    const int m0  = (wg >> 3) * BM;     // 64 m-tiles
    const int n0  = (wg & 7) * BN;      // 8 n-tiles

    // staging geometry: one STG = 8 waves x 64 lanes x 16B = 64 rows of 128B
    const int srow   = lane >> 3;                 // row within wave's 8-row chunk
    const int schunk = (lane & 7) ^ srow;         // permuted global chunk
    const int selem  = schunk * 8;                // bf16 offset within row
    const int grow   = w * 8 + srow;              // row within 64-row chunk

    const int quad = lane >> 4;
    const int l16  = lane & 15;
    const int swz  = l16 & 7;
    const int coff0 = ((0 * 4 + quad) ^ swz) << 3;   // kstep 0 chunk offset (elems)
    const int coff1 = ((1 * 4 + quad) ^ swz) << 3;   // kstep 1

    int arow[8], brow[4];
#pragma unroll
    for (int f = 0; f < 8; ++f) arow[f] = (wm * 128 + f * 16 + l16) * BK;
#pragma unroll
    for (int j = 0; j < 4; ++j) brow[j] = (wn * 64 + j * 16 + l16) * BK;

    u16* As0 = &lds[0][0][0];
    u16* Bs0 = &lds[0][1][0];
    u16* As1 = &lds[1][0][0];
    u16* Bs1 = &lds[1][1][0];

    const u16* ga = xb + (size_t)m0 * KDIM;
    const u16* gb = wb + (size_t)n0 * KDIM;

#define STG(dstbase, gsrc, rb, kk)                                             \
    async_copy16((gsrc) + (size_t)((rb) + grow) * KDIM + (size_t)(kk) + selem, \
                 (char*)(dstbase) + ((rb) + w * 8) * (BK * 2))

#define BAR do { asm volatile("" ::: "memory");                   \
                 __builtin_amdgcn_s_barrier();                    \
                 asm volatile("" ::: "memory"); } while (0)
#define LGK0 asm volatile("s_waitcnt lgkmcnt(0)" ::: "memory")
#define VM4  asm volatile("s_waitcnt vmcnt(4)" ::: "memory")

#define LDA_QUAD(base, q)                                                      \
    _Pragma("unroll")                                                          \
    for (int i = 0; i < 2; ++i) {                                              \
        af[i][0] = *(const bf16x8*)((base) + arow[(q) * 2 + i] + coff0);       \
        af[i][1] = *(const bf16x8*)((base) + arow[(q) * 2 + i] + coff1);       \
    }

#define LDB_ALL(base)                                                          \
    _Pragma("unroll")                                                          \
    for (int j = 0; j < 4; ++j) {                                              \
        bf[j][0] = *(const bf16x8*)((base) + brow[j] + coff0);                 \
        bf[j][1] = *(const bf16x8*)((base) + brow[j] + coff1);                 \
    }

// 16 MFMAs: quadrant q (rowfrags 2q,2q+1) x 4 colfrags x 2 ksteps.
// s-outer order: 8 independent MFMAs per s-group.
#define MFMA16(q) do {                                                         \
    __builtin_amdgcn_s_setprio(1);                                             \
    _Pragma("unroll")                                                          \
    for (int s = 0; s < 2; ++s)                                                \
        _Pragma("unroll")                                                      \
        for (int j = 0; j < 4; ++j)                                            \
            _Pragma("unroll")                                                  \
            for (int i = 0; i < 2; ++i)                                        \
                acc[(q) * 2 + i][j] = __builtin_amdgcn_mfma_f32_16x16x32_bf16( \
                    af[i][s], bf[j][s], acc[(q) * 2 + i][j], 0, 0, 0);         \
    __builtin_amdgcn_s_setprio(0);                                             \
} while (0)

    // ---- prologue: tile0 A+B -> buf0 (8 loads), B(tile1) -> buf1 (4 loads)
    STG(As0, ga, 0, 0); STG(As0, ga, 64, 0); STG(As0, ga, 128, 0); STG(As0, ga, 192, 0);
    STG(Bs0, gb, 0, 0); STG(Bs0, gb, 64, 0); STG(Bs0, gb, 128, 0); STG(Bs0, gb, 192, 0);
    STG(Bs1, gb, 0, BK); STG(Bs1, gb, 64, BK); STG(Bs1, gb, 128, BK); STG(Bs1, gb, 192, BK);

    f32x4 acc[8][4];
#pragma unroll
    for (int i = 0; i < 8; ++i)
#pragma unroll
        for (int j = 0; j < 4; ++j)
            acc[i][j] = (f32x4){0.f, 0.f, 0.f, 0.f};

    bf16x8 af[2][2], bf[4][2];

    VM4;   // tile0's 8 loads landed; B(1)'s 4 still in flight
    BAR;

#pragma unroll 1
    for (int it = 0; it < NITER; ++it) {
        const int t   = 2 * it;
        const int ka1 = (t + 1) * BK;                  // <= 31*64, never wraps
        const int kb2 = ((t + 2) & (NTILE - 1)) * BK;  // wraps harmlessly at tail
        const int kb3 = ((t + 3) & (NTILE - 1)) * BK;

        // ---- P1: tile t (buf0): B all + A quad0; stage A(t+1)->buf1 ----
        LDB_ALL(Bs0); LDA_QUAD(As0, 0);
        STG(As1, ga, 0, ka1); STG(As1, ga, 64, ka1);
        STG(As1, ga, 128, ka1); STG(As1, ga, 192, ka1);
        BAR; LGK0; MFMA16(0); BAR;

        // ---- P2: A quad1; stage B(t+2) rows 0-127 -> buf0 ----
        LDA_QUAD(As0, 1);
        STG(Bs0, gb, 0, kb2); STG(Bs0, gb, 64, kb2);
        BAR; LGK0; MFMA16(1); BAR;

        // ---- P3: A quad2; stage B(t+2) rows 128-255 -> buf0 ----
        LDA_QUAD(As0, 2);
        STG(Bs0, gb, 128, kb2); STG(Bs0, gb, 192, kb2);
        BAR; LGK0; MFMA16(2); BAR;

        // ---- P4: A quad3; counted wait ----
        LDA_QUAD(As0, 3);
        BAR; LGK0; MFMA16(3);
        VM4;   // A(t+1), B(t+1) landed; B(t+2) (4 loads) stays in flight
        BAR;

        // ---- P5: tile t+1 (buf1): B all + A quad0; stage A(t+2)->buf0 ----
        LDB_ALL(Bs1); LDA_QUAD(As1, 0);
        STG(As0, ga, 0, kb2); STG(As0, ga, 64, kb2);
        STG(As0, ga, 128, kb2); STG(As0, ga, 192, kb2);
        BAR; LGK0; MFMA16(0); BAR;

        // ---- P6: A quad1; stage B(t+3) rows 0-127 -> buf1 ----
        LDA_QUAD(As1, 1);
        STG(Bs1, gb, 0, kb3); STG(Bs1, gb, 64, kb3);
        BAR; LGK0; MFMA16(1); BAR;

        // ---- P7: A quad2; stage B(t+3) rows 128-255 -> buf1 ----
        LDA_QUAD(As1, 2);
        STG(Bs1, gb, 128, kb3); STG(Bs1, gb, 192, kb3);
        BAR; LGK0; MFMA16(2); BAR;

        // ---- P8: A quad3; counted wait ----
        LDA_QUAD(As1, 3);
        BAR; LGK0; MFMA16(3);
        VM4;   // A(t+2), B(t+2) landed; B(t+3) stays in flight
        BAR;
    }

    // ---- epilogue: C/D layout col=lane&15, row=quad*4+reg (verified) ----
#pragma unroll
    for (int j = 0; j < 4; ++j) {
        const int col = n0 + wn * 64 + j * 16 + l16;
        const float bj = bias[col];
#pragma unroll
        for (int f = 0; f < 8; ++f) {
            const int rowb = m0 + wm * 128 + f * 16 + quad * 4;
#pragma unroll
            for (int r = 0; r < 4; ++r)
                out[(size_t)(rowb + r) * NDIM + col] = acc[f][j][r] + bj;
        }
    }

#undef STG
#undef BAR
#undef LGK0
#undef VM4
#undef LDA_QUAD
#undef LDB_ALL
#undef MFMA16
}

extern "C" void kernel_launch(void* const* d_in, const int* in_sizes, int n_in,
                              void* d_out, int out_size, void* d_ws, size_t ws_size,
                              hipStream_t stream) {
    const float* x    = (const float*)d_in[0];   // [8,2048,2048]
    const float* W    = (const float*)d_in[1];   // [2048,2048] row-major [o,d]
    const float* bias = (const float*)d_in[2];   // [2048]
    const float* Bm   = (const float*)d_in[3];   // [2048,16]
    const float* Am   = (const float*)d_in[4];   // [16,2048]
    float* out = (float*)d_out;

    u16* xb   = (u16*)d_ws;                      // 16384*2048 bf16 = 64 MB
    u16* wbuf = xb + (size_t)MDIM * KDIM;        // 2048*2048 bf16 = 8 MB

    prep<<<WPREP_BLOCKS + XCONV_BLOCKS, 256, 0, stream>>>(x, W, Bm, Am, xb, wbuf);

    dim3 grid((MDIM / BM) * (NDIM / BN));        // 512 blocks
    gemm_bt<<<grid, 512, 0, stream>>>(xb, wbuf, bias, out);
}